// Round 1
// baseline (800.937 us; speedup 1.0000x reference)
//
#include <hip/hip_runtime.h>

// GCN x2: out = A_hat @ (relu(A_hat @ x @ W1 + b1)) @ W2 + b2
// Restructured as (A_hat @ x) @ W1 so edge traffic stays in S=4 dim.

__global__ void k_init(float* __restrict__ deg, float4* __restrict__ agg1, int n) {
    int i = blockIdx.x * blockDim.x + threadIdx.x;
    if (i < n) {
        deg[i] = 1.0f;  // self-loop contributes 1 to degree
        agg1[i] = make_float4(0.f, 0.f, 0.f, 0.f);
    }
}

__global__ void k_count(const int* __restrict__ col, float* __restrict__ deg, int e) {
    int i = blockIdx.x * blockDim.x + threadIdx.x;
    if (i < e) atomicAdd(&deg[col[i]], 1.0f);
}

__global__ void k_dinv(float* __restrict__ deg, int n) {
    int i = blockIdx.x * blockDim.x + threadIdx.x;
    if (i < n) deg[i] = rsqrtf(deg[i]);  // deg >= 1 always (self-loops)
}

// dst[c] += src[r] * dinv[r]*dinv[c], one thread per edge
__global__ void k_scatter(const int* __restrict__ row, const int* __restrict__ col,
                          const float* __restrict__ dinv,
                          const float4* __restrict__ src, float* __restrict__ dst, int e) {
    int i = blockIdx.x * blockDim.x + threadIdx.x;
    if (i < e) {
        int r = row[i], c = col[i];
        float w = dinv[r] * dinv[c];
        float4 v = src[r];
        atomicAdd(&dst[c * 4 + 0], v.x * w);
        atomicAdd(&dst[c * 4 + 1], v.y * w);
        atomicAdd(&dst[c * 4 + 2], v.z * w);
        atomicAdd(&dst[c * 4 + 3], v.w * w);
    }
}

// Per node: a = agg1[i] + x[i]*dinv^2 (self-loop); h = relu(a@W1 + b1);
// t = h@W2; out[i] = b2 + t*dinv^2 (conv2 self-loop, also zero-inits out).
__global__ void k_node_mid(const float4* __restrict__ agg1, const float4* __restrict__ x,
                           const float* __restrict__ dinv,
                           const float* __restrict__ W1, const float* __restrict__ b1,
                           const float* __restrict__ W2, const float* __restrict__ b2,
                           float4* __restrict__ t, float4* __restrict__ out, int n) {
    int i = blockIdx.x * blockDim.x + threadIdx.x;
    if (i >= n) return;
    float di = dinv[i];
    float sl = di * di;
    float4 a = agg1[i];
    float4 xv = x[i];
    float a0 = a.x + xv.x * sl;
    float a1 = a.y + xv.y * sl;
    float a2 = a.z + xv.z * sl;
    float a3 = a.w + xv.w * sl;
    float t0 = 0.f, t1 = 0.f, t2 = 0.f, t3 = 0.f;
#pragma unroll 8
    for (int j = 0; j < 64; ++j) {
        // W1 is [4][64] row-major; uniform addresses -> scalar loads
        float h = b1[j] + a0 * W1[j] + a1 * W1[64 + j] + a2 * W1[128 + j] + a3 * W1[192 + j];
        h = fmaxf(h, 0.f);
        // W2 is [64][4] row-major
        t0 += h * W2[j * 4 + 0];
        t1 += h * W2[j * 4 + 1];
        t2 += h * W2[j * 4 + 2];
        t3 += h * W2[j * 4 + 3];
    }
    t[i] = make_float4(t0, t1, t2, t3);
    out[i] = make_float4(b2[0] + t0 * sl, b2[1] + t1 * sl,
                         b2[2] + t2 * sl, b2[3] + t3 * sl);
}

extern "C" void kernel_launch(void* const* d_in, const int* in_sizes, int n_in,
                              void* d_out, int out_size, void* d_ws, size_t ws_size,
                              hipStream_t stream) {
    const float* x  = (const float*)d_in[0];
    const int* edge = (const int*)d_in[1];
    const float* W1 = (const float*)d_in[2];
    const float* b1 = (const float*)d_in[3];
    const float* W2 = (const float*)d_in[4];
    const float* b2 = (const float*)d_in[5];
    float* out = (float*)d_out;

    const int n = in_sizes[0] / 4;      // N nodes (S=4)
    const int e = in_sizes[1] / 2;      // E edges
    const int* row = edge;              // edge_index[0]
    const int* col = edge + e;          // edge_index[1]

    float* deg  = (float*)d_ws;         // N floats (becomes dinv in place)
    float* agg1 = deg + n;              // 4N floats
    float* t    = agg1 + 4 * n;         // 4N floats

    const int B = 256;
    const int gn = (n + B - 1) / B;
    const int ge = (e + B - 1) / B;

    k_init<<<gn, B, 0, stream>>>(deg, (float4*)agg1, n);
    k_count<<<ge, B, 0, stream>>>(col, deg, e);
    k_dinv<<<gn, B, 0, stream>>>(deg, n);
    k_scatter<<<ge, B, 0, stream>>>(row, col, deg, (const float4*)x, agg1, e);
    k_node_mid<<<gn, B, 0, stream>>>((const float4*)agg1, (const float4*)x, deg,
                                     W1, b1, W2, b2, (float4*)t, (float4*)out, n);
    k_scatter<<<ge, B, 0, stream>>>(row, col, deg, (const float4*)t, out, e);
}

// Round 2
// 224.586 us; speedup vs baseline: 3.5663x; 3.5663x over previous
//
#include <hip/hip_runtime.h>

// GCN x2 via destination-bucketed edges (counting sort) + LDS accumulation.
// out = A_hat @ (relu((A_hat @ x) @ W1 + b1) @ W2) + b2
// No random global atomics: each 128-node bucket is owned by one workgroup.

#define BSHIFT 7
#define BNODES 128          // nodes per bucket
#define EPB    4096         // edges per block in hist/fill
#define KMAX   1024         // max buckets (N<=131072)

__global__ void k_zero(int* __restrict__ count, int K) {
    for (int k = threadIdx.x; k < K; k += blockDim.x) count[k] = 0;
}

__global__ void k_hist(const int* __restrict__ col, int e, int K,
                       int* __restrict__ count) {
    __shared__ int h[KMAX];
    for (int k = threadIdx.x; k < K; k += blockDim.x) h[k] = 0;
    __syncthreads();
    int lo = blockIdx.x * EPB, hi = min(lo + EPB, e);
    for (int i = lo + threadIdx.x; i < hi; i += blockDim.x)
        atomicAdd(&h[col[i] >> BSHIFT], 1);
    __syncthreads();
    for (int k = threadIdx.x; k < K; k += blockDim.x)
        if (h[k]) atomicAdd(&count[k], h[k]);
}

__global__ void k_scan(const int* __restrict__ count, int K,
                       int* __restrict__ base, int* __restrict__ cursor) {
    __shared__ int s[KMAX];
    int t = threadIdx.x;
    int v = (t < K) ? count[t] : 0;
    s[t] = v;
    __syncthreads();
    for (int off = 1; off < KMAX; off <<= 1) {
        int u = (t >= off) ? s[t - off] : 0;
        __syncthreads();
        s[t] += u;
        __syncthreads();
    }
    if (t < K) { base[t] = s[t] - v; cursor[t] = s[t] - v; }
}

__global__ void k_fill(const int* __restrict__ row, const int* __restrict__ col,
                       int e, int K, int* __restrict__ cursor,
                       int2* __restrict__ ere) {
    __shared__ int h[KMAX];
    __shared__ int lbase[KMAX];
    for (int k = threadIdx.x; k < K; k += blockDim.x) h[k] = 0;
    __syncthreads();
    int lo = blockIdx.x * EPB, hi = min(lo + EPB, e);
    for (int i = lo + threadIdx.x; i < hi; i += blockDim.x)
        atomicAdd(&h[col[i] >> BSHIFT], 1);
    __syncthreads();
    for (int k = threadIdx.x; k < K; k += blockDim.x)
        lbase[k] = h[k] ? atomicAdd(&cursor[k], h[k]) : 0;
    __syncthreads();
    for (int k = threadIdx.x; k < K; k += blockDim.x) h[k] = 0;  // reuse as local cursor
    __syncthreads();
    for (int i = lo + threadIdx.x; i < hi; i += blockDim.x) {
        int c = col[i];
        int b = c >> BSHIFT;
        int rk = atomicAdd(&h[b], 1);
        ere[lbase[b] + rk] = make_int2(row[i], c);
    }
}

__global__ void k_deg_dinv(const int2* __restrict__ ere, const int* __restrict__ base,
                           const int* __restrict__ count, float* __restrict__ dinv, int n) {
    __shared__ int cnt[BNODES];
    int b = blockIdx.x, nlo = b << BSHIFT, t = threadIdx.x;
    if (t < BNODES) cnt[t] = 0;
    __syncthreads();
    int lo = base[b], hi = lo + count[b];
    for (int i = lo + t; i < hi; i += blockDim.x)
        atomicAdd(&cnt[ere[i].y - nlo], 1);
    __syncthreads();
    int node = nlo + t;
    if (t < BNODES && node < n)
        dinv[node] = rsqrtf((float)cnt[t] + 1.0f);  // +1 self-loop
}

// dst[c] (=|+=) sum over bucket edges of src[r]*dinv[r]*dinv[c]
__global__ void k_accum(const int2* __restrict__ ere, const int* __restrict__ base,
                        const int* __restrict__ count, const float* __restrict__ dinv,
                        const float4* __restrict__ src, float4* __restrict__ dst,
                        int n, int addmode) {
    __shared__ float acc[4 * BNODES];  // transposed: acc[j*BNODES+c] -> bank = c%32
    __shared__ float dl[BNODES];
    int b = blockIdx.x, nlo = b << BSHIFT, t = threadIdx.x;
    for (int k = t; k < 4 * BNODES; k += blockDim.x) acc[k] = 0.f;
    if (t < BNODES) {
        int node = nlo + t;
        dl[t] = (node < n) ? dinv[node] : 0.f;
    }
    __syncthreads();
    int lo = base[b], hi = lo + count[b];
    for (int i = lo + t; i < hi; i += blockDim.x) {
        int2 rc = ere[i];
        int cl = rc.y - nlo;
        float w = dinv[rc.x] * dl[cl];
        float4 v = src[rc.x];
        atomicAdd(&acc[0 * BNODES + cl], v.x * w);
        atomicAdd(&acc[1 * BNODES + cl], v.y * w);
        atomicAdd(&acc[2 * BNODES + cl], v.z * w);
        atomicAdd(&acc[3 * BNODES + cl], v.w * w);
    }
    __syncthreads();
    int node = nlo + t;
    if (t < BNODES && node < n) {
        float4 o = make_float4(acc[t], acc[BNODES + t], acc[2 * BNODES + t], acc[3 * BNODES + t]);
        if (addmode) {
            float4 p = dst[node];
            o.x += p.x; o.y += p.y; o.z += p.z; o.w += p.w;
        }
        dst[node] = o;
    }
}

// a = agg1[i] + x[i]*dinv^2; h = relu(a@W1+b1); t = h@W2;
// out[i] = b2 + t*dinv^2   (full overwrite -> initializes out)
__global__ void k_node_mid(const float4* __restrict__ agg1, const float4* __restrict__ x,
                           const float* __restrict__ dinv,
                           const float* __restrict__ W1, const float* __restrict__ b1,
                           const float* __restrict__ W2, const float* __restrict__ b2,
                           float4* __restrict__ t, float4* __restrict__ out, int n) {
    int i = blockIdx.x * blockDim.x + threadIdx.x;
    if (i >= n) return;
    float di = dinv[i];
    float sl = di * di;
    float4 a = agg1[i];
    float4 xv = x[i];
    float a0 = a.x + xv.x * sl;
    float a1 = a.y + xv.y * sl;
    float a2 = a.z + xv.z * sl;
    float a3 = a.w + xv.w * sl;
    float t0 = 0.f, t1 = 0.f, t2 = 0.f, t3 = 0.f;
#pragma unroll 8
    for (int j = 0; j < 64; ++j) {
        float h = b1[j] + a0 * W1[j] + a1 * W1[64 + j] + a2 * W1[128 + j] + a3 * W1[192 + j];
        h = fmaxf(h, 0.f);
        t0 += h * W2[j * 4 + 0];
        t1 += h * W2[j * 4 + 1];
        t2 += h * W2[j * 4 + 2];
        t3 += h * W2[j * 4 + 3];
    }
    t[i] = make_float4(t0, t1, t2, t3);
    out[i] = make_float4(b2[0] + t0 * sl, b2[1] + t1 * sl,
                         b2[2] + t2 * sl, b2[3] + t3 * sl);
}

extern "C" void kernel_launch(void* const* d_in, const int* in_sizes, int n_in,
                              void* d_out, int out_size, void* d_ws, size_t ws_size,
                              hipStream_t stream) {
    const float* x  = (const float*)d_in[0];
    const int* edge = (const int*)d_in[1];
    const float* W1 = (const float*)d_in[2];
    const float* b1 = (const float*)d_in[3];
    const float* W2 = (const float*)d_in[4];
    const float* b2 = (const float*)d_in[5];
    float* out = (float*)d_out;

    const int n = in_sizes[0] / 4;   // N nodes (S=4)
    const int e = in_sizes[1] / 2;   // E edges
    const int* row = edge;
    const int* col = edge + e;
    const int K = (n + BNODES - 1) >> BSHIFT;   // buckets (782 for N=100000)

    // workspace layout (all 4-byte elems; float4 segs are 16B-aligned)
    char* ws = (char*)d_ws;
    float* agg1 = (float*)ws;                       ws += (size_t)4 * n * 4;
    float* tmid = (float*)ws;                       ws += (size_t)4 * n * 4;
    float* dinv = (float*)ws;                       ws += (size_t)n * 4;
    int2*  ere  = (int2*)ws;                        ws += (size_t)e * 8;
    int*   cnt  = (int*)ws;                         ws += (size_t)K * 4;
    int*   base = (int*)ws;                         ws += (size_t)K * 4;
    int*   cur  = (int*)ws;                         ws += (size_t)K * 4;

    const int B = 256;
    const int gn = (n + B - 1) / B;
    const int ge = (e + EPB - 1) / EPB;

    k_zero<<<1, 1024, 0, stream>>>(cnt, K);
    k_hist<<<ge, B, 0, stream>>>(col, e, K, cnt);
    k_scan<<<1, KMAX, 0, stream>>>(cnt, K, base, cur);
    k_fill<<<ge, B, 0, stream>>>(row, col, e, K, cur, ere);
    k_deg_dinv<<<K, B, 0, stream>>>(ere, base, cnt, dinv, n);
    k_accum<<<K, B, 0, stream>>>(ere, base, cnt, dinv, (const float4*)x,
                                 (float4*)agg1, n, 0);
    k_node_mid<<<gn, B, 0, stream>>>((const float4*)agg1, (const float4*)x, dinv,
                                     W1, b1, W2, b2, (float4*)tmid, (float4*)out, n);
    k_accum<<<K, B, 0, stream>>>(ere, base, cnt, dinv, (const float4*)tmid,
                                 (float4*)out, n, 1);
}